// Round 1
// baseline (1145.649 us; speedup 1.0000x reference)
//
#include <hip/hip_runtime.h>
#include <hip/hip_bf16.h>

#define NN 100000
#define EE 3200000
#define NG 8
#define EPSBN 1e-5f

// ---------------- init: deg=1 (self loop), cnt=0, accumulators=0 ----------------
__global__ void k_init(float* deg, int* cnt, float* accum) {
    int i = blockIdx.x * blockDim.x + threadIdx.x;
    if (i < NN) { deg[i] = 1.0f; cnt[i] = 0; }
    if (i < 1024) accum[i] = 0.0f;
}

// ---------------- weighted degree + integer count per destination ----------------
__global__ void k_degcnt(const int* __restrict__ ei, const float* __restrict__ ew,
                         float* deg, int* cnt) {
    int e = blockIdx.x * blockDim.x + threadIdx.x;
    if (e < EE) {
        int c = ei[EE + e];
        atomicAdd(&deg[c], ew[e]);
        atomicAdd(&cnt[c], 1);
    }
}

// ---------------- deg -> deg^-1/2 in place (deg >= 1 always) ----------------
__global__ void k_dinv(float* deg) {
    int i = blockIdx.x * blockDim.x + threadIdx.x;
    if (i < NN) deg[i] = 1.0f / sqrtf(deg[i]);
}

// ---------------- prefix sum over counts: 3-phase scan ----------------
#define NCH 196  // ceil(100000/512)
__global__ void k_scan_a(const int* __restrict__ cnt, int* csums) {
    __shared__ int sd[256];
    int b = blockIdx.x, t = threadIdx.x;
    int i0 = b * 512 + t, i1 = i0 + 256;
    int v = ((i0 < NN) ? cnt[i0] : 0) + ((i1 < NN) ? cnt[i1] : 0);
    sd[t] = v; __syncthreads();
    for (int off = 128; off > 0; off >>= 1) {
        if (t < off) sd[t] += sd[t + off];
        __syncthreads();
    }
    if (t == 0) csums[b] = sd[0];
}
__global__ void k_scan_b(const int* csums, int* coffs) {
    if (threadIdx.x == 0) {
        int r = 0;
        for (int i = 0; i < NCH; i++) { coffs[i] = r; r += csums[i]; }
    }
}
__global__ void k_scan_c(const int* __restrict__ cnt, const int* __restrict__ coffs,
                         int* rstart, int* cursor) {
    __shared__ int sd[256];
    int b = blockIdx.x, t = threadIdx.x;
    int i0 = b * 512 + 2 * t;
    int c0 = (i0 < NN) ? cnt[i0] : 0;
    int c1 = (i0 + 1 < NN) ? cnt[i0 + 1] : 0;
    int s = c0 + c1;
    sd[t] = s; __syncthreads();
    for (int off = 1; off < 256; off <<= 1) {
        int v = (t >= off) ? sd[t - off] : 0;
        __syncthreads();
        sd[t] += v;
        __syncthreads();
    }
    int excl = sd[t] - s + coffs[b];
    if (i0 < NN)     { rstart[i0] = excl;          cursor[i0] = excl; }
    if (i0 + 1 < NN) { rstart[i0 + 1] = excl + c0; cursor[i0 + 1] = excl + c0; }
}

// ---------------- fill CSR records: (src, norm) packed in 8B ----------------
__global__ void k_fill(const int* __restrict__ ei, const float* __restrict__ ew,
                       const float* __restrict__ dinv, int* cursor,
                       unsigned long long* __restrict__ csr) {
    int e = blockIdx.x * blockDim.x + threadIdx.x;
    if (e < EE) {
        int r = ei[e], c = ei[EE + e];
        float nv = dinv[r] * ew[e] * dinv[c];
        int p = atomicAdd(&cursor[c], 1);
        csr[p] = ((unsigned long long)__float_as_uint(nv) << 32) | (unsigned int)r;
    }
}

// ---------------- BN0 stats over x [N,13] ----------------
__global__ void k_bn0stats(const float* __restrict__ x, float* st) {
    __shared__ float ls[13], lq[13];
    int t = threadIdx.x;
    if (t < 13) { ls[t] = 0.f; lq[t] = 0.f; }
    __syncthreads();
    int stride = gridDim.x * blockDim.x;
    for (int idx = blockIdx.x * blockDim.x + t; idx < NN * 13; idx += stride) {
        float v = x[idx];
        int c = idx % 13;
        atomicAdd(&ls[c], v);
        atomicAdd(&lq[c], v * v);
    }
    __syncthreads();
    if (t < 13) { atomicAdd(&st[t], ls[t]); atomicAdd(&st[13 + t], lq[t]); }
}

// ---------------- fold BN0 into W1: Wp = diag(s)W1, cp = t.W1 ----------------
__global__ void k_fold0(const float* st, const float* __restrict__ g0,
                        const float* __restrict__ be0, const float* __restrict__ W1,
                        float* Wp, float* cp) {
    int t = threadIdx.x;
    if (t < 13 * 32) {
        int k = t >> 5;
        float mu = st[k] * (1.0f / NN);
        float var = st[13 + k] * (1.0f / NN) - mu * mu;
        float s = g0[k] / sqrtf(var + EPSBN);
        Wp[t] = s * W1[t];
    }
    if (t < 32) {
        float acc = 0.f;
        for (int k = 0; k < 13; k++) {
            float mu = st[k] * (1.0f / NN);
            float var = st[13 + k] * (1.0f / NN) - mu * mu;
            float s = g0[k] / sqrtf(var + EPSBN);
            float tt = be0[k] - mu * s;
            acc += tt * W1[k * 32 + t];
        }
        cp[t] = acc;
    }
}

// ---------------- fold BN_l into W_{l+1} (32 channels) ----------------
__global__ void k_fold(const float* st, const float* __restrict__ g,
                       const float* __restrict__ be, const float* __restrict__ W,
                       float* Wp, float* cp) {
    int t = threadIdx.x;  // 1024
    {
        int k = t >> 5;
        float mu = st[k] * (1.0f / NN);
        float var = st[32 + k] * (1.0f / NN) - mu * mu;
        float s = g[k] / sqrtf(var + EPSBN);
        Wp[t] = s * W[t];
    }
    if (t < 32) {
        float acc = 0.f;
        for (int k = 0; k < 32; k++) {
            float mu = st[k] * (1.0f / NN);
            float var = st[32 + k] * (1.0f / NN) - mu * mu;
            float s = g[k] / sqrtf(var + EPSBN);
            float tt = be[k] - mu * s;
            acc += tt * W[k * 32 + t];
        }
        cp[t] = acc;
    }
}

// ---------------- a = x @ Wp + cp  (13 -> 32), half-wave per node ----------------
__global__ void k_gemm_in(const float* __restrict__ x, const float* __restrict__ Wp,
                          const float* __restrict__ cp, float* __restrict__ a) {
    __shared__ float w[13 * 32];
    __shared__ float cb[32];
    int t = threadIdx.x;
    for (int i = t; i < 13 * 32; i += 256) w[i] = Wp[i];
    if (t < 32) cb[t] = cp[t];
    __syncthreads();
    int hw = (blockIdx.x * 256 + t) >> 5;
    int lane = t & 31;
    if (hw < NN) {
        float v = (lane < 13) ? x[hw * 13 + lane] : 0.f;
        float acc = cb[lane];
        #pragma unroll
        for (int k = 0; k < 13; k++)
            acc = fmaf(__shfl(v, k, 32), w[k * 32 + lane], acc);
        a[hw * 32 + lane] = acc;
    }
}

// ---------------- a = h @ Wp + cp  (32 -> 32), half-wave per node ----------------
__global__ void k_gemm(const float* __restrict__ h, const float* __restrict__ Wp,
                       const float* __restrict__ cp, float* __restrict__ a) {
    __shared__ float w[1024];
    __shared__ float cb[32];
    int t = threadIdx.x;
    for (int i = t; i < 1024; i += 256) w[i] = Wp[i];
    if (t < 32) cb[t] = cp[t];
    __syncthreads();
    int hw = (blockIdx.x * 256 + t) >> 5;
    int lane = t & 31;
    if (hw < NN) {
        float v = h[hw * 32 + lane];
        float acc = cb[lane];
        #pragma unroll
        for (int k = 0; k < 32; k++)
            acc = fmaf(__shfl(v, k, 32), w[k * 32 + lane], acc);
        a[hw * 32 + lane] = acc;
    }
}

// ------- gather: y = relu(A_norm @ a + b), accumulate BN stats (sum, sumsq) -------
__global__ void k_gather(const float* __restrict__ a, const float* __restrict__ dinv,
                         const int* __restrict__ rstart, const int* __restrict__ cnt,
                         const unsigned long long* __restrict__ csr,
                         const float* __restrict__ bias,
                         float* __restrict__ y, float* st) {
    int t = threadIdx.x;
    int lane = t & 31;
    int hw0 = (blockIdx.x * blockDim.x + t) >> 5;
    int nhw = (gridDim.x * blockDim.x) >> 5;
    float bv = bias[lane];
    float bsum = 0.f, bsq = 0.f;
    for (int node = hw0; node < NN; node += nhw) {
        float di = dinv[node];
        float acc = bv + di * di * a[node * 32 + lane];
        int s0 = rstart[node], n = cnt[node];
        const unsigned long long* rec = csr + s0;
        int j = 0;
        for (; j + 4 <= n; j += 4) {
            unsigned long long r0 = rec[j], r1 = rec[j + 1], r2 = rec[j + 2], r3 = rec[j + 3];
            float v0 = a[(int)(unsigned int)r0 * 32 + lane];
            float v1 = a[(int)(unsigned int)r1 * 32 + lane];
            float v2 = a[(int)(unsigned int)r2 * 32 + lane];
            float v3 = a[(int)(unsigned int)r3 * 32 + lane];
            acc = fmaf(__uint_as_float((unsigned int)(r0 >> 32)), v0, acc);
            acc = fmaf(__uint_as_float((unsigned int)(r1 >> 32)), v1, acc);
            acc = fmaf(__uint_as_float((unsigned int)(r2 >> 32)), v2, acc);
            acc = fmaf(__uint_as_float((unsigned int)(r3 >> 32)), v3, acc);
        }
        for (; j < n; j++) {
            unsigned long long r0 = rec[j];
            acc = fmaf(__uint_as_float((unsigned int)(r0 >> 32)),
                       a[(int)(unsigned int)r0 * 32 + lane], acc);
        }
        acc = fmaxf(acc, 0.f);
        y[node * 32 + lane] = acc;
        bsum += acc;
        bsq += acc * acc;
    }
    // stats reduction: pair nodes within wave, then LDS, then global
    bsum += __shfl_xor(bsum, 32);
    bsq  += __shfl_xor(bsq, 32);
    __shared__ float ls[32], lq[32];
    if (t < 32) { ls[t] = 0.f; lq[t] = 0.f; }
    __syncthreads();
    if ((t & 32) == 0) { atomicAdd(&ls[lane], bsum); atomicAdd(&lq[lane], bsq); }
    __syncthreads();
    if (t < 32) { atomicAdd(&st[t], ls[t]); atomicAdd(&st[32 + t], lq[t]); }
}

// ---------------- per-graph sums of y4 ----------------
__global__ void k_pool(const float* __restrict__ y, const int* __restrict__ bat,
                       float* gsum, float* gcnt) {
    __shared__ float ls[NG * 32];
    __shared__ float lc[NG];
    int t = threadIdx.x, lane = t & 31;
    if (t < NG * 32) ls[t] = 0.f;
    if (t < NG) lc[t] = 0.f;
    __syncthreads();
    int hw0 = (blockIdx.x * blockDim.x + t) >> 5;
    int nhw = (gridDim.x * blockDim.x) >> 5;
    for (int node = hw0; node < NN; node += nhw) {
        int g = bat[node];
        atomicAdd(&ls[g * 32 + lane], y[node * 32 + lane]);
        if (lane == 0) atomicAdd(&lc[g], 1.0f);
    }
    __syncthreads();
    if (t < NG * 32) atomicAdd(&gsum[t], ls[t]);
    if (t < NG) atomicAdd(&gcnt[t], lc[t]);
}

// ---------------- final: BN4 fold + mean pool ----------------
__global__ void k_final(const float* st, const float* gsum, const float* gcnt,
                        const float* __restrict__ g4, const float* __restrict__ be4,
                        float* out) {
    int t = threadIdx.x;  // 256
    int gg = t >> 5, c = t & 31;
    float mu = st[c] * (1.0f / NN);
    float var = st[32 + c] * (1.0f / NN) - mu * mu;
    float s = g4[c] / sqrtf(var + EPSBN);
    float tt = be4[c] - mu * s;
    float cv = fmaxf(gcnt[gg], 1.0f);
    out[gg * 32 + c] = (gsum[gg * 32 + c] / cv) * s + tt;
}

extern "C" void kernel_launch(void* const* d_in, const int* in_sizes, int n_in,
                              void* d_out, int out_size, void* d_ws, size_t ws_size,
                              hipStream_t stream) {
    const float* x   = (const float*)d_in[0];
    const int*   ei  = (const int*)d_in[1];
    const float* ew  = (const float*)d_in[2];
    const int*   bat = (const int*)d_in[3];
    const float* W1  = (const float*)d_in[4];
    const float* b1  = (const float*)d_in[5];
    const float* W2  = (const float*)d_in[6];
    const float* b2  = (const float*)d_in[7];
    const float* W3  = (const float*)d_in[8];
    const float* b3  = (const float*)d_in[9];
    const float* W4  = (const float*)d_in[10];
    const float* b4  = (const float*)d_in[11];
    const float* g0  = (const float*)d_in[12];
    const float* be0 = (const float*)d_in[13];
    const float* g1  = (const float*)d_in[14];
    const float* be1 = (const float*)d_in[15];
    const float* g2  = (const float*)d_in[16];
    const float* be2 = (const float*)d_in[17];
    const float* g3  = (const float*)d_in[18];
    const float* be3 = (const float*)d_in[19];
    const float* g4  = (const float*)d_in[20];
    const float* be4 = (const float*)d_in[21];

    // workspace bump allocator (512B aligned segments)
    char* ws = (char*)d_ws;
    size_t off = 0;
    auto alloc = [&](size_t bytes) -> char* {
        char* p = ws + off;
        off = (off + bytes + 511) & ~(size_t)511;
        return p;
    };
    float* deg    = (float*)alloc(NN * 4);          // becomes dinv in place
    int*   cnt    = (int*)alloc(NN * 4);
    int*   rstart = (int*)alloc(NN * 4);
    int*   cursor = (int*)alloc(NN * 4);
    int*   csums  = (int*)alloc(256 * 4);
    int*   coffs  = (int*)alloc(256 * 4);
    float* accum  = (float*)alloc(1024 * 4);
    float* Wp     = (float*)alloc(1056 * 4);
    float* cp     = Wp + 1024;
    float* abuf   = (float*)alloc((size_t)NN * 32 * 4);
    float* ybuf   = (float*)alloc((size_t)NN * 32 * 4);
    unsigned long long* csr = (unsigned long long*)alloc((size_t)EE * 8);
    if (off > ws_size) return;  // workspace too small: fail loudly

    float* st0 = accum;         // 26 used
    float* st1 = accum + 64;
    float* st2 = accum + 128;
    float* st3 = accum + 192;
    float* st4 = accum + 256;
    float* gsum = accum + 320;  // 256
    float* gcnt = accum + 576;  // 8

    const int GN = (NN + 255) / 256;      // 391
    const int GE = (EE + 255) / 256;      // 12500
    const int GNODE = (NN * 32 + 255) / 256;  // 12500 (half-wave per node)

    k_init<<<GN, 256, 0, stream>>>(deg, cnt, accum);
    k_degcnt<<<GE, 256, 0, stream>>>(ei, ew, deg, cnt);
    k_dinv<<<GN, 256, 0, stream>>>(deg);
    k_scan_a<<<NCH, 256, 0, stream>>>(cnt, csums);
    k_scan_b<<<1, 64, 0, stream>>>(csums, coffs);
    k_scan_c<<<NCH, 256, 0, stream>>>(cnt, coffs, rstart, cursor);
    k_fill<<<GE, 256, 0, stream>>>(ei, ew, deg, cursor, csr);
    k_bn0stats<<<512, 256, 0, stream>>>(x, st0);
    k_fold0<<<1, 512, 0, stream>>>(st0, g0, be0, W1, Wp, cp);
    k_gemm_in<<<GNODE, 256, 0, stream>>>(x, Wp, cp, abuf);
    k_gather<<<2048, 256, 0, stream>>>(abuf, deg, rstart, cnt, csr, b1, ybuf, st1);
    k_fold<<<1, 1024, 0, stream>>>(st1, g1, be1, W2, Wp, cp);
    k_gemm<<<GNODE, 256, 0, stream>>>(ybuf, Wp, cp, abuf);
    k_gather<<<2048, 256, 0, stream>>>(abuf, deg, rstart, cnt, csr, b2, ybuf, st2);
    k_fold<<<1, 1024, 0, stream>>>(st2, g2, be2, W3, Wp, cp);
    k_gemm<<<GNODE, 256, 0, stream>>>(ybuf, Wp, cp, abuf);
    k_gather<<<2048, 256, 0, stream>>>(abuf, deg, rstart, cnt, csr, b3, ybuf, st3);
    k_fold<<<1, 1024, 0, stream>>>(st3, g3, be3, W4, Wp, cp);
    k_gemm<<<GNODE, 256, 0, stream>>>(ybuf, Wp, cp, abuf);
    k_gather<<<2048, 256, 0, stream>>>(abuf, deg, rstart, cnt, csr, b4, ybuf, st4);
    k_pool<<<512, 256, 0, stream>>>(ybuf, bat, gsum, gcnt);
    k_final<<<1, 256, 0, stream>>>(st4, gsum, gcnt, g4, be4, (float*)d_out);
}

// Round 2
// 809.723 us; speedup vs baseline: 1.4149x; 1.4149x over previous
//
#include <hip/hip_runtime.h>
#include <hip/hip_bf16.h>

#define NN 100000
#define EE 3200000
#define NG 8
#define EPSBN 1e-5f

// counting-sort geometry: 256 coarse buckets of 391 nodes, fixed-stride regions
#define NB 256
#define NPB 391          // 256*391 = 100096 >= NN
#define CAPB 13312       // mean 12500, sigma ~112 -> +7.25 sigma headroom
#define CHUNK 4096       // edges per k_bucket block

// ---------------- init: bucket cursors + accumulators ----------------
__global__ void k_init(int* bktcur, float* accum) {
    int i = blockIdx.x * blockDim.x + threadIdx.x;
    if (i < NB) bktcur[i] = 0;
    if (i < 1024) accum[i] = 0.0f;
}

// ---- pass A: scatter edges into coarse buckets (per-block LDS histogram,
//      one global atomic per (block,bucket) to reserve space) ----
__global__ void k_bucket(const int* __restrict__ ei, const float* __restrict__ ew,
                         int* bktcur, unsigned long long* __restrict__ recs) {
    __shared__ int hist[NB];
    int t = threadIdx.x;  // 256
    hist[t] = 0;
    __syncthreads();
    int e0 = blockIdx.x * CHUNK;
    int eend = min(e0 + CHUNK, EE);
    for (int e = e0 + t; e < eend; e += 256) {
        int c = ei[EE + e];
        atomicAdd(&hist[c / NPB], 1);
    }
    __syncthreads();
    int h = hist[t];
    __syncthreads();
    if (h > 0) hist[t] = atomicAdd(&bktcur[t], h);  // global reserve; hist[t]=start
    __syncthreads();
    for (int e = e0 + t; e < eend; e += 256) {
        int r = ei[e];
        int c = ei[EE + e];
        float w = ew[e];
        int b = c / NPB;
        int crel = c - b * NPB;
        int pos = atomicAdd(&hist[b], 1);  // LDS cursor -> global slot in bucket b
        if (pos < CAPB) {
            recs[(size_t)b * CAPB + pos] =
                ((unsigned long long)__float_as_uint(w) << 32) |
                ((unsigned long long)((unsigned int)crel) << 17) | (unsigned int)r;
        }
    }
}

// ---- pass B1: per-bucket node counts + weighted degree (LDS), scan -> rstart,
//      write dinv/cnt/rstart ----
__global__ void k_b1(const int* __restrict__ bktcur,
                     const unsigned long long* __restrict__ recs,
                     float* __restrict__ dinvg, int* __restrict__ cntg,
                     int* __restrict__ rstart) {
    __shared__ int co[512];
    __shared__ int sc[512];
    __shared__ float dl[NPB];
    int b = blockIdx.x, t = threadIdx.x;  // 256 threads
    co[t] = 0; co[t + 256] = 0;
    for (int i = t; i < NPB; i += 256) dl[i] = 0.f;
    __syncthreads();
    int nrec = min(bktcur[b], CAPB);
    const unsigned long long* rp = recs + (size_t)b * CAPB;
    for (int i = t; i < nrec; i += 256) {
        unsigned long long rec = rp[i];
        int crel = (int)((rec >> 17) & 511u);
        float w = __uint_as_float((unsigned int)(rec >> 32));
        atomicAdd(&co[crel], 1);
        atomicAdd(&dl[crel], w);
    }
    __syncthreads();
    sc[t] = co[t]; sc[t + 256] = co[t + 256];
    __syncthreads();
    for (int off = 1; off < 512; off <<= 1) {
        int v0 = (t >= off) ? sc[t - off] : 0;
        int v1 = (t + 256 >= off) ? sc[t + 256 - off] : 0;
        __syncthreads();
        sc[t] += v0; sc[t + 256] += v1;
        __syncthreads();
    }
    for (int i = t; i < NPB; i += 256) {
        int node = b * NPB + i;
        if (node < NN) {
            dinvg[node] = 1.0f / sqrtf(dl[i] + 1.0f);  // +1 self-loop
            cntg[node] = co[i];
            rstart[node] = b * CAPB + (sc[i] - co[i]); // exclusive scan, absolute
        }
    }
}

// ---- pass B2: per-bucket CSR fill via LDS cursors; norm = dinv[r]*w*dinv[c] ----
__global__ void k_b2(const int* __restrict__ bktcur,
                     const unsigned long long* __restrict__ recs,
                     const float* __restrict__ dinvg,
                     const int* __restrict__ rstart,
                     unsigned long long* __restrict__ csr) {
    __shared__ int cur[NPB];
    __shared__ float dloc[NPB];
    int b = blockIdx.x, t = threadIdx.x;
    for (int i = t; i < NPB; i += 256) {
        int node = b * NPB + i;
        if (node < NN) { cur[i] = rstart[node]; dloc[i] = dinvg[node]; }
        else { cur[i] = 0; dloc[i] = 0.f; }
    }
    __syncthreads();
    int nrec = min(bktcur[b], CAPB);
    const unsigned long long* rp = recs + (size_t)b * CAPB;
    for (int i = t; i < nrec; i += 256) {
        unsigned long long rec = rp[i];
        int r = (int)(rec & 0x1FFFFu);
        int crel = (int)((rec >> 17) & 511u);
        float w = __uint_as_float((unsigned int)(rec >> 32));
        float nv = dinvg[r] * w * dloc[crel];
        int slot = atomicAdd(&cur[crel], 1);
        csr[slot] = ((unsigned long long)__float_as_uint(nv) << 32) | (unsigned int)r;
    }
}

// ---------------- BN0 stats over x [N,13] ----------------
__global__ void k_bn0stats(const float* __restrict__ x, float* st) {
    __shared__ float ls[13], lq[13];
    int t = threadIdx.x;
    if (t < 13) { ls[t] = 0.f; lq[t] = 0.f; }
    __syncthreads();
    int stride = gridDim.x * blockDim.x;
    for (int idx = blockIdx.x * blockDim.x + t; idx < NN * 13; idx += stride) {
        float v = x[idx];
        int c = idx % 13;
        atomicAdd(&ls[c], v);
        atomicAdd(&lq[c], v * v);
    }
    __syncthreads();
    if (t < 13) { atomicAdd(&st[t], ls[t]); atomicAdd(&st[13 + t], lq[t]); }
}

// ---------------- fold BN0 into W1 ----------------
__global__ void k_fold0(const float* st, const float* __restrict__ g0,
                        const float* __restrict__ be0, const float* __restrict__ W1,
                        float* Wp, float* cp) {
    int t = threadIdx.x;
    if (t < 13 * 32) {
        int k = t >> 5;
        float mu = st[k] * (1.0f / NN);
        float var = st[13 + k] * (1.0f / NN) - mu * mu;
        float s = g0[k] / sqrtf(var + EPSBN);
        Wp[t] = s * W1[t];
    }
    if (t < 32) {
        float acc = 0.f;
        for (int k = 0; k < 13; k++) {
            float mu = st[k] * (1.0f / NN);
            float var = st[13 + k] * (1.0f / NN) - mu * mu;
            float s = g0[k] / sqrtf(var + EPSBN);
            float tt = be0[k] - mu * s;
            acc += tt * W1[k * 32 + t];
        }
        cp[t] = acc;
    }
}

// ---------------- fold BN_l into W_{l+1} (32 channels) ----------------
__global__ void k_fold(const float* st, const float* __restrict__ g,
                       const float* __restrict__ be, const float* __restrict__ W,
                       float* Wp, float* cp) {
    int t = threadIdx.x;  // 1024
    {
        int k = t >> 5;
        float mu = st[k] * (1.0f / NN);
        float var = st[32 + k] * (1.0f / NN) - mu * mu;
        float s = g[k] / sqrtf(var + EPSBN);
        Wp[t] = s * W[t];
    }
    if (t < 32) {
        float acc = 0.f;
        for (int k = 0; k < 32; k++) {
            float mu = st[k] * (1.0f / NN);
            float var = st[32 + k] * (1.0f / NN) - mu * mu;
            float s = g[k] / sqrtf(var + EPSBN);
            float tt = be[k] - mu * s;
            acc += tt * W[k * 32 + t];
        }
        cp[t] = acc;
    }
}

// ---------------- a = x @ Wp + cp  (13 -> 32), half-wave per node ----------------
__global__ void k_gemm_in(const float* __restrict__ x, const float* __restrict__ Wp,
                          const float* __restrict__ cp, float* __restrict__ a) {
    __shared__ float w[13 * 32];
    __shared__ float cb[32];
    int t = threadIdx.x;
    for (int i = t; i < 13 * 32; i += 256) w[i] = Wp[i];
    if (t < 32) cb[t] = cp[t];
    __syncthreads();
    int hw = (blockIdx.x * 256 + t) >> 5;
    int lane = t & 31;
    if (hw < NN) {
        float v = (lane < 13) ? x[hw * 13 + lane] : 0.f;
        float acc = cb[lane];
        #pragma unroll
        for (int k = 0; k < 13; k++)
            acc = fmaf(__shfl(v, k, 32), w[k * 32 + lane], acc);
        a[hw * 32 + lane] = acc;
    }
}

// ---------------- a = h @ Wp + cp  (32 -> 32), half-wave per node ----------------
__global__ void k_gemm(const float* __restrict__ h, const float* __restrict__ Wp,
                       const float* __restrict__ cp, float* __restrict__ a) {
    __shared__ float w[1024];
    __shared__ float cb[32];
    int t = threadIdx.x;
    for (int i = t; i < 1024; i += 256) w[i] = Wp[i];
    if (t < 32) cb[t] = cp[t];
    __syncthreads();
    int hw = (blockIdx.x * 256 + t) >> 5;
    int lane = t & 31;
    if (hw < NN) {
        float v = h[hw * 32 + lane];
        float acc = cb[lane];
        #pragma unroll
        for (int k = 0; k < 32; k++)
            acc = fmaf(__shfl(v, k, 32), w[k * 32 + lane], acc);
        a[hw * 32 + lane] = acc;
    }
}

// ------- gather: y = relu(A_norm @ a + b), accumulate BN stats (sum, sumsq) -------
__global__ void k_gather(const float* __restrict__ a, const float* __restrict__ dinv,
                         const int* __restrict__ rstart, const int* __restrict__ cnt,
                         const unsigned long long* __restrict__ csr,
                         const float* __restrict__ bias,
                         float* __restrict__ y, float* st) {
    int t = threadIdx.x;
    int lane = t & 31;
    int hw0 = (blockIdx.x * blockDim.x + t) >> 5;
    int nhw = (gridDim.x * blockDim.x) >> 5;
    float bv = bias[lane];
    float bsum = 0.f, bsq = 0.f;
    for (int node = hw0; node < NN; node += nhw) {
        float di = dinv[node];
        float acc = bv + di * di * a[node * 32 + lane];
        int s0 = rstart[node], n = cnt[node];
        const unsigned long long* rec = csr + s0;
        int j = 0;
        for (; j + 4 <= n; j += 4) {
            unsigned long long r0 = rec[j], r1 = rec[j + 1], r2 = rec[j + 2], r3 = rec[j + 3];
            float v0 = a[(int)(unsigned int)(r0 & 0xFFFFFFFFu) * 32 + lane];
            float v1 = a[(int)(unsigned int)(r1 & 0xFFFFFFFFu) * 32 + lane];
            float v2 = a[(int)(unsigned int)(r2 & 0xFFFFFFFFu) * 32 + lane];
            float v3 = a[(int)(unsigned int)(r3 & 0xFFFFFFFFu) * 32 + lane];
            acc = fmaf(__uint_as_float((unsigned int)(r0 >> 32)), v0, acc);
            acc = fmaf(__uint_as_float((unsigned int)(r1 >> 32)), v1, acc);
            acc = fmaf(__uint_as_float((unsigned int)(r2 >> 32)), v2, acc);
            acc = fmaf(__uint_as_float((unsigned int)(r3 >> 32)), v3, acc);
        }
        for (; j < n; j++) {
            unsigned long long r0 = rec[j];
            acc = fmaf(__uint_as_float((unsigned int)(r0 >> 32)),
                       a[(int)(unsigned int)(r0 & 0xFFFFFFFFu) * 32 + lane], acc);
        }
        acc = fmaxf(acc, 0.f);
        y[node * 32 + lane] = acc;
        bsum += acc;
        bsq += acc * acc;
    }
    bsum += __shfl_xor(bsum, 32);
    bsq  += __shfl_xor(bsq, 32);
    __shared__ float ls[32], lq[32];
    if (t < 32) { ls[t] = 0.f; lq[t] = 0.f; }
    __syncthreads();
    if ((t & 32) == 0) { atomicAdd(&ls[lane], bsum); atomicAdd(&lq[lane], bsq); }
    __syncthreads();
    if (t < 32) { atomicAdd(&st[t], ls[t]); atomicAdd(&st[32 + t], lq[t]); }
}

// ---------------- per-graph sums of y4 ----------------
__global__ void k_pool(const float* __restrict__ y, const int* __restrict__ bat,
                       float* gsum, float* gcnt) {
    __shared__ float ls[NG * 32];
    __shared__ float lc[NG];
    int t = threadIdx.x, lane = t & 31;
    if (t < NG * 32) ls[t] = 0.f;
    if (t < NG) lc[t] = 0.f;
    __syncthreads();
    int hw0 = (blockIdx.x * blockDim.x + t) >> 5;
    int nhw = (gridDim.x * blockDim.x) >> 5;
    for (int node = hw0; node < NN; node += nhw) {
        int g = bat[node];
        atomicAdd(&ls[g * 32 + lane], y[node * 32 + lane]);
        if (lane == 0) atomicAdd(&lc[g], 1.0f);
    }
    __syncthreads();
    if (t < NG * 32) atomicAdd(&gsum[t], ls[t]);
    if (t < NG) atomicAdd(&gcnt[t], lc[t]);
}

// ---------------- final: BN4 fold + mean pool ----------------
__global__ void k_final(const float* st, const float* gsum, const float* gcnt,
                        const float* __restrict__ g4, const float* __restrict__ be4,
                        float* out) {
    int t = threadIdx.x;  // 256
    int gg = t >> 5, c = t & 31;
    float mu = st[c] * (1.0f / NN);
    float var = st[32 + c] * (1.0f / NN) - mu * mu;
    float s = g4[c] / sqrtf(var + EPSBN);
    float tt = be4[c] - mu * s;
    float cv = fmaxf(gcnt[gg], 1.0f);
    out[gg * 32 + c] = (gsum[gg * 32 + c] / cv) * s + tt;
}

extern "C" void kernel_launch(void* const* d_in, const int* in_sizes, int n_in,
                              void* d_out, int out_size, void* d_ws, size_t ws_size,
                              hipStream_t stream) {
    const float* x   = (const float*)d_in[0];
    const int*   ei  = (const int*)d_in[1];
    const float* ew  = (const float*)d_in[2];
    const int*   bat = (const int*)d_in[3];
    const float* W1  = (const float*)d_in[4];
    const float* b1  = (const float*)d_in[5];
    const float* W2  = (const float*)d_in[6];
    const float* b2  = (const float*)d_in[7];
    const float* W3  = (const float*)d_in[8];
    const float* b3  = (const float*)d_in[9];
    const float* W4  = (const float*)d_in[10];
    const float* b4  = (const float*)d_in[11];
    const float* g0  = (const float*)d_in[12];
    const float* be0 = (const float*)d_in[13];
    const float* g1  = (const float*)d_in[14];
    const float* be1 = (const float*)d_in[15];
    const float* g2  = (const float*)d_in[16];
    const float* be2 = (const float*)d_in[17];
    const float* g3  = (const float*)d_in[18];
    const float* be3 = (const float*)d_in[19];
    const float* g4  = (const float*)d_in[20];
    const float* be4 = (const float*)d_in[21];

    char* ws = (char*)d_ws;
    size_t off = 0;
    auto alloc = [&](size_t bytes) -> char* {
        char* p = ws + off;
        off = (off + bytes + 511) & ~(size_t)511;
        return p;
    };
    float* dinvg  = (float*)alloc(NN * 4);
    int*   cntg   = (int*)alloc(NN * 4);
    int*   rstart = (int*)alloc(NN * 4);
    int*   bktcur = (int*)alloc(NB * 4);
    float* accum  = (float*)alloc(1024 * 4);
    float* Wp     = (float*)alloc(1056 * 4);
    float* cp     = Wp + 1024;
    unsigned long long* recs = (unsigned long long*)alloc((size_t)NB * CAPB * 8);
    unsigned long long* csr  = (unsigned long long*)alloc((size_t)NB * CAPB * 8);
    if (off > ws_size) return;  // workspace too small: fail loudly
    // abuf/ybuf alias the bucket-record region (recs dead after k_b2)
    float* abuf = (float*)recs;
    float* ybuf = abuf + (size_t)NN * 32;

    float* st0 = accum;
    float* st1 = accum + 64;
    float* st2 = accum + 128;
    float* st3 = accum + 192;
    float* st4 = accum + 256;
    float* gsum = accum + 320;
    float* gcnt = accum + 576;

    const int GE = (EE + CHUNK - 1) / CHUNK;         // 782
    const int GNODE = (NN * 32 + 255) / 256;         // 12500 half-wave-per-node

    k_init<<<4, 256, 0, stream>>>(bktcur, accum);
    k_bucket<<<GE, 256, 0, stream>>>(ei, ew, bktcur, recs);
    k_b1<<<NB, 256, 0, stream>>>(bktcur, recs, dinvg, cntg, rstart);
    k_b2<<<NB, 256, 0, stream>>>(bktcur, recs, dinvg, rstart, csr);
    k_bn0stats<<<512, 256, 0, stream>>>(x, st0);
    k_fold0<<<1, 512, 0, stream>>>(st0, g0, be0, W1, Wp, cp);
    k_gemm_in<<<GNODE, 256, 0, stream>>>(x, Wp, cp, abuf);
    k_gather<<<2048, 256, 0, stream>>>(abuf, dinvg, rstart, cntg, csr, b1, ybuf, st1);
    k_fold<<<1, 1024, 0, stream>>>(st1, g1, be1, W2, Wp, cp);
    k_gemm<<<GNODE, 256, 0, stream>>>(ybuf, Wp, cp, abuf);
    k_gather<<<2048, 256, 0, stream>>>(abuf, dinvg, rstart, cntg, csr, b2, ybuf, st2);
    k_fold<<<1, 1024, 0, stream>>>(st2, g2, be2, W3, Wp, cp);
    k_gemm<<<GNODE, 256, 0, stream>>>(ybuf, Wp, cp, abuf);
    k_gather<<<2048, 256, 0, stream>>>(abuf, dinvg, rstart, cntg, csr, b3, ybuf, st3);
    k_fold<<<1, 1024, 0, stream>>>(st3, g3, be3, W4, Wp, cp);
    k_gemm<<<GNODE, 256, 0, stream>>>(ybuf, Wp, cp, abuf);
    k_gather<<<2048, 256, 0, stream>>>(abuf, dinvg, rstart, cntg, csr, b4, ybuf, st4);
    k_pool<<<512, 256, 0, stream>>>(ybuf, bat, gsum, gcnt);
    k_final<<<1, 256, 0, stream>>>(st4, gsum, gcnt, g4, be4, (float*)d_out);
}

// Round 3
// 779.364 us; speedup vs baseline: 1.4700x; 1.0390x over previous
//
#include <hip/hip_runtime.h>
#include <hip/hip_bf16.h>

#define NN 100000
#define EE 3200000
#define NG 8
#define EPSBN 1e-5f

// counting-sort geometry: 256 coarse buckets of 391 nodes, fixed-stride regions
#define NB 256
#define NPB 391          // 256*391 = 100096 >= NN
#define CAPB 13312       // mean 12500, sigma ~112 -> +7.25 sigma headroom
#define CHUNK 4096       // edges per k_bucket block

// ---------------- init: bucket cursors + accumulators ----------------
__global__ void k_init(int* bktcur, float* accum) {
    int i = blockIdx.x * blockDim.x + threadIdx.x;
    if (i < NB) bktcur[i] = 0;
    if (i < 1024) accum[i] = 0.0f;
}

// ---- pass A: scatter edges into coarse buckets (per-block LDS histogram,
//      one global atomic per (block,bucket) to reserve space) ----
__global__ void k_bucket(const int* __restrict__ ei, const float* __restrict__ ew,
                         int* bktcur, unsigned long long* __restrict__ recs) {
    __shared__ int hist[NB];
    int t = threadIdx.x;  // 256
    hist[t] = 0;
    __syncthreads();
    int e0 = blockIdx.x * CHUNK;
    int eend = min(e0 + CHUNK, EE);
    for (int e = e0 + t; e < eend; e += 256) {
        int c = ei[EE + e];
        atomicAdd(&hist[c / NPB], 1);
    }
    __syncthreads();
    int h = hist[t];
    __syncthreads();
    if (h > 0) hist[t] = atomicAdd(&bktcur[t], h);  // global reserve; hist[t]=start
    __syncthreads();
    for (int e = e0 + t; e < eend; e += 256) {
        int r = ei[e];
        int c = ei[EE + e];
        float w = ew[e];
        int b = c / NPB;
        int crel = c - b * NPB;
        int pos = atomicAdd(&hist[b], 1);  // LDS cursor -> global slot in bucket b
        if (pos < CAPB) {
            recs[(size_t)b * CAPB + pos] =
                ((unsigned long long)__float_as_uint(w) << 32) |
                ((unsigned long long)((unsigned int)crel) << 17) | (unsigned int)r;
        }
    }
}

// ---- pass B1: per-bucket node counts + weighted degree (LDS), scan -> rstart,
//      write dinv/cnt/rstart ----
__global__ void k_b1(const int* __restrict__ bktcur,
                     const unsigned long long* __restrict__ recs,
                     float* __restrict__ dinvg, int* __restrict__ cntg,
                     int* __restrict__ rstart) {
    __shared__ int co[512];
    __shared__ int sc[512];
    __shared__ float dl[NPB];
    int b = blockIdx.x, t = threadIdx.x;  // 256 threads
    co[t] = 0; co[t + 256] = 0;
    for (int i = t; i < NPB; i += 256) dl[i] = 0.f;
    __syncthreads();
    int nrec = min(bktcur[b], CAPB);
    const unsigned long long* rp = recs + (size_t)b * CAPB;
    for (int i = t; i < nrec; i += 256) {
        unsigned long long rec = rp[i];
        int crel = (int)((rec >> 17) & 511u);
        float w = __uint_as_float((unsigned int)(rec >> 32));
        atomicAdd(&co[crel], 1);
        atomicAdd(&dl[crel], w);
    }
    __syncthreads();
    sc[t] = co[t]; sc[t + 256] = co[t + 256];
    __syncthreads();
    for (int off = 1; off < 512; off <<= 1) {
        int v0 = (t >= off) ? sc[t - off] : 0;
        int v1 = (t + 256 >= off) ? sc[t + 256 - off] : 0;
        __syncthreads();
        sc[t] += v0; sc[t + 256] += v1;
        __syncthreads();
    }
    for (int i = t; i < NPB; i += 256) {
        int node = b * NPB + i;
        if (node < NN) {
            dinvg[node] = 1.0f / sqrtf(dl[i] + 1.0f);  // +1 self-loop
            cntg[node] = co[i];
            rstart[node] = b * CAPB + (sc[i] - co[i]); // exclusive scan, absolute
        }
    }
}

// ---- pass B2: per-bucket CSR fill via LDS cursors; norm = dinv[r]*w*dinv[c] ----
__global__ void k_b2(const int* __restrict__ bktcur,
                     const unsigned long long* __restrict__ recs,
                     const float* __restrict__ dinvg,
                     const int* __restrict__ rstart,
                     unsigned long long* __restrict__ csr) {
    __shared__ int cur[NPB];
    __shared__ float dloc[NPB];
    int b = blockIdx.x, t = threadIdx.x;
    for (int i = t; i < NPB; i += 256) {
        int node = b * NPB + i;
        if (node < NN) { cur[i] = rstart[node]; dloc[i] = dinvg[node]; }
        else { cur[i] = 0; dloc[i] = 0.f; }
    }
    __syncthreads();
    int nrec = min(bktcur[b], CAPB);
    const unsigned long long* rp = recs + (size_t)b * CAPB;
    for (int i = t; i < nrec; i += 256) {
        unsigned long long rec = rp[i];
        int r = (int)(rec & 0x1FFFFu);
        int crel = (int)((rec >> 17) & 511u);
        float w = __uint_as_float((unsigned int)(rec >> 32));
        float nv = dinvg[r] * w * dloc[crel];
        int slot = atomicAdd(&cur[crel], 1);
        csr[slot] = ((unsigned long long)__float_as_uint(nv) << 32) | (unsigned int)r;
    }
}

// ---------------- BN0 stats over x [N,13] ----------------
__global__ void k_bn0stats(const float* __restrict__ x, float* st) {
    __shared__ float ls[13], lq[13];
    int t = threadIdx.x;
    if (t < 13) { ls[t] = 0.f; lq[t] = 0.f; }
    __syncthreads();
    int stride = gridDim.x * blockDim.x;
    for (int idx = blockIdx.x * blockDim.x + t; idx < NN * 13; idx += stride) {
        float v = x[idx];
        int c = idx % 13;
        atomicAdd(&ls[c], v);
        atomicAdd(&lq[c], v * v);
    }
    __syncthreads();
    if (t < 13) { atomicAdd(&st[t], ls[t]); atomicAdd(&st[13 + t], lq[t]); }
}

// ---------------- fold BN0 into W1 ----------------
__global__ void k_fold0(const float* st, const float* __restrict__ g0,
                        const float* __restrict__ be0, const float* __restrict__ W1,
                        float* Wp, float* cp) {
    int t = threadIdx.x;
    if (t < 13 * 32) {
        int k = t >> 5;
        float mu = st[k] * (1.0f / NN);
        float var = st[13 + k] * (1.0f / NN) - mu * mu;
        float s = g0[k] / sqrtf(var + EPSBN);
        Wp[t] = s * W1[t];
    }
    if (t < 32) {
        float acc = 0.f;
        for (int k = 0; k < 13; k++) {
            float mu = st[k] * (1.0f / NN);
            float var = st[13 + k] * (1.0f / NN) - mu * mu;
            float s = g0[k] / sqrtf(var + EPSBN);
            float tt = be0[k] - mu * s;
            acc += tt * W1[k * 32 + t];
        }
        cp[t] = acc;
    }
}

// ---------------- fold BN_l into W_{l+1} (32 channels) ----------------
__global__ void k_fold(const float* st, const float* __restrict__ g,
                       const float* __restrict__ be, const float* __restrict__ W,
                       float* Wp, float* cp) {
    int t = threadIdx.x;  // 1024
    {
        int k = t >> 5;
        float mu = st[k] * (1.0f / NN);
        float var = st[32 + k] * (1.0f / NN) - mu * mu;
        float s = g[k] / sqrtf(var + EPSBN);
        Wp[t] = s * W[t];
    }
    if (t < 32) {
        float acc = 0.f;
        for (int k = 0; k < 32; k++) {
            float mu = st[k] * (1.0f / NN);
            float var = st[32 + k] * (1.0f / NN) - mu * mu;
            float s = g[k] / sqrtf(var + EPSBN);
            float tt = be[k] - mu * s;
            acc += tt * W[k * 32 + t];
        }
        cp[t] = acc;
    }
}

// ---------------- a = x @ Wp + cp  (13 -> 32), half-wave per node ----------------
__global__ void k_gemm_in(const float* __restrict__ x, const float* __restrict__ Wp,
                          const float* __restrict__ cp, float* __restrict__ a) {
    __shared__ float w[13 * 32];
    __shared__ float cb[32];
    int t = threadIdx.x;
    for (int i = t; i < 13 * 32; i += 256) w[i] = Wp[i];
    if (t < 32) cb[t] = cp[t];
    __syncthreads();
    int hw = (blockIdx.x * 256 + t) >> 5;
    int lane = t & 31;
    if (hw < NN) {
        float v = (lane < 13) ? x[hw * 13 + lane] : 0.f;
        float acc = cb[lane];
        #pragma unroll
        for (int k = 0; k < 13; k++)
            acc = fmaf(__shfl(v, k, 32), w[k * 32 + lane], acc);
        a[hw * 32 + lane] = acc;
    }
}

// ---------------- a = h @ Wp + cp  (32 -> 32), half-wave per node ----------------
__global__ void k_gemm(const float* __restrict__ h, const float* __restrict__ Wp,
                       const float* __restrict__ cp, float* __restrict__ a) {
    __shared__ float w[1024];
    __shared__ float cb[32];
    int t = threadIdx.x;
    for (int i = t; i < 1024; i += 256) w[i] = Wp[i];
    if (t < 32) cb[t] = cp[t];
    __syncthreads();
    int hw = (blockIdx.x * 256 + t) >> 5;
    int lane = t & 31;
    if (hw < NN) {
        float v = h[hw * 32 + lane];
        float acc = cb[lane];
        #pragma unroll
        for (int k = 0; k < 32; k++)
            acc = fmaf(__shfl(v, k, 32), w[k * 32 + lane], acc);
        a[hw * 32 + lane] = acc;
    }
}

// ------- gather: y = relu(A_norm @ a + b), accumulate BN stats (sum, sumsq) -------
// Lane geometry per 32-lane half-wave (one node): 4 edge-subgroups x 8 channel-
// groups; each lane loads float4 (4 channels of 1 edge) -> one dwordx4 per wave
// covers 8 edges, unroll-by-2 gives 8 independent load chains per half-wave.
__global__ void k_gather(const float* __restrict__ a, const float* __restrict__ dinv,
                         const int* __restrict__ rstart, const int* __restrict__ cnt,
                         const unsigned long long* __restrict__ csr,
                         const float* __restrict__ bias,
                         float* __restrict__ y, float* st) {
    int t = threadIdx.x;
    int hl = t & 31;          // lane within half-wave
    int eg = hl >> 3;         // edge subgroup 0..3
    int cg = hl & 7;          // channel group -> channels 4cg..4cg+3
    int hw0 = (blockIdx.x * blockDim.x + t) >> 5;
    int nhw = (gridDim.x * blockDim.x) >> 5;
    const float4* a4 = (const float4*)a;
    float4 bv = ((const float4*)bias)[cg];
    float4 bsum = {0.f, 0.f, 0.f, 0.f}, bsq = {0.f, 0.f, 0.f, 0.f};
    for (int node = hw0; node < NN; node += nhw) {
        float di = dinv[node];
        float4 acc;
        if (eg == 0) {
            float4 self = a4[node * 8 + cg];
            float dd = di * di;
            acc.x = bv.x + dd * self.x;
            acc.y = bv.y + dd * self.y;
            acc.z = bv.z + dd * self.z;
            acc.w = bv.w + dd * self.w;
        } else {
            acc.x = acc.y = acc.z = acc.w = 0.f;
        }
        int s0 = rstart[node], n = cnt[node];
        const unsigned long long* rec = csr + s0;
        int j = eg;
        for (; j + 4 < n; j += 8) {
            unsigned long long r0 = rec[j];
            unsigned long long r1 = rec[j + 4];
            float4 v0 = a4[(int)(unsigned int)(r0 & 0xFFFFFFFFu) * 8 + cg];
            float4 v1 = a4[(int)(unsigned int)(r1 & 0xFFFFFFFFu) * 8 + cg];
            float n0 = __uint_as_float((unsigned int)(r0 >> 32));
            float n1 = __uint_as_float((unsigned int)(r1 >> 32));
            acc.x = fmaf(n0, v0.x, acc.x);
            acc.y = fmaf(n0, v0.y, acc.y);
            acc.z = fmaf(n0, v0.z, acc.z);
            acc.w = fmaf(n0, v0.w, acc.w);
            acc.x = fmaf(n1, v1.x, acc.x);
            acc.y = fmaf(n1, v1.y, acc.y);
            acc.z = fmaf(n1, v1.z, acc.z);
            acc.w = fmaf(n1, v1.w, acc.w);
        }
        if (j < n) {
            unsigned long long r0 = rec[j];
            float4 v0 = a4[(int)(unsigned int)(r0 & 0xFFFFFFFFu) * 8 + cg];
            float n0 = __uint_as_float((unsigned int)(r0 >> 32));
            acc.x = fmaf(n0, v0.x, acc.x);
            acc.y = fmaf(n0, v0.y, acc.y);
            acc.z = fmaf(n0, v0.z, acc.z);
            acc.w = fmaf(n0, v0.w, acc.w);
        }
        // reduce over the 4 edge-subgroups (lane bits 3,4; stays within half-wave)
        acc.x += __shfl_xor(acc.x, 8);
        acc.y += __shfl_xor(acc.y, 8);
        acc.z += __shfl_xor(acc.z, 8);
        acc.w += __shfl_xor(acc.w, 8);
        acc.x += __shfl_xor(acc.x, 16);
        acc.y += __shfl_xor(acc.y, 16);
        acc.z += __shfl_xor(acc.z, 16);
        acc.w += __shfl_xor(acc.w, 16);
        if (eg == 0) {
            acc.x = fmaxf(acc.x, 0.f);
            acc.y = fmaxf(acc.y, 0.f);
            acc.z = fmaxf(acc.z, 0.f);
            acc.w = fmaxf(acc.w, 0.f);
            ((float4*)y)[node * 8 + cg] = acc;
            bsum.x += acc.x; bsum.y += acc.y; bsum.z += acc.z; bsum.w += acc.w;
            bsq.x += acc.x * acc.x; bsq.y += acc.y * acc.y;
            bsq.z += acc.z * acc.z; bsq.w += acc.w * acc.w;
        }
    }
    __shared__ float ls[32], lq[32];
    if (t < 32) { ls[t] = 0.f; lq[t] = 0.f; }
    __syncthreads();
    if (eg == 0) {
        int c = cg * 4;
        atomicAdd(&ls[c + 0], bsum.x); atomicAdd(&ls[c + 1], bsum.y);
        atomicAdd(&ls[c + 2], bsum.z); atomicAdd(&ls[c + 3], bsum.w);
        atomicAdd(&lq[c + 0], bsq.x);  atomicAdd(&lq[c + 1], bsq.y);
        atomicAdd(&lq[c + 2], bsq.z);  atomicAdd(&lq[c + 3], bsq.w);
    }
    __syncthreads();
    if (t < 32) { atomicAdd(&st[t], ls[t]); atomicAdd(&st[32 + t], lq[t]); }
}

// ---------------- per-graph sums of y4 ----------------
__global__ void k_pool(const float* __restrict__ y, const int* __restrict__ bat,
                       float* gsum, float* gcnt) {
    __shared__ float ls[NG * 32];
    __shared__ float lc[NG];
    int t = threadIdx.x, lane = t & 31;
    if (t < NG * 32) ls[t] = 0.f;
    if (t < NG) lc[t] = 0.f;
    __syncthreads();
    int hw0 = (blockIdx.x * blockDim.x + t) >> 5;
    int nhw = (gridDim.x * blockDim.x) >> 5;
    for (int node = hw0; node < NN; node += nhw) {
        int g = bat[node];
        atomicAdd(&ls[g * 32 + lane], y[node * 32 + lane]);
        if (lane == 0) atomicAdd(&lc[g], 1.0f);
    }
    __syncthreads();
    if (t < NG * 32) atomicAdd(&gsum[t], ls[t]);
    if (t < NG) atomicAdd(&gcnt[t], lc[t]);
}

// ---------------- final: BN4 fold + mean pool ----------------
__global__ void k_final(const float* st, const float* gsum, const float* gcnt,
                        const float* __restrict__ g4, const float* __restrict__ be4,
                        float* out) {
    int t = threadIdx.x;  // 256
    int gg = t >> 5, c = t & 31;
    float mu = st[c] * (1.0f / NN);
    float var = st[32 + c] * (1.0f / NN) - mu * mu;
    float s = g4[c] / sqrtf(var + EPSBN);
    float tt = be4[c] - mu * s;
    float cv = fmaxf(gcnt[gg], 1.0f);
    out[gg * 32 + c] = (gsum[gg * 32 + c] / cv) * s + tt;
}

extern "C" void kernel_launch(void* const* d_in, const int* in_sizes, int n_in,
                              void* d_out, int out_size, void* d_ws, size_t ws_size,
                              hipStream_t stream) {
    const float* x   = (const float*)d_in[0];
    const int*   ei  = (const int*)d_in[1];
    const float* ew  = (const float*)d_in[2];
    const int*   bat = (const int*)d_in[3];
    const float* W1  = (const float*)d_in[4];
    const float* b1  = (const float*)d_in[5];
    const float* W2  = (const float*)d_in[6];
    const float* b2  = (const float*)d_in[7];
    const float* W3  = (const float*)d_in[8];
    const float* b3  = (const float*)d_in[9];
    const float* W4  = (const float*)d_in[10];
    const float* b4  = (const float*)d_in[11];
    const float* g0  = (const float*)d_in[12];
    const float* be0 = (const float*)d_in[13];
    const float* g1  = (const float*)d_in[14];
    const float* be1 = (const float*)d_in[15];
    const float* g2  = (const float*)d_in[16];
    const float* be2 = (const float*)d_in[17];
    const float* g3  = (const float*)d_in[18];
    const float* be3 = (const float*)d_in[19];
    const float* g4  = (const float*)d_in[20];
    const float* be4 = (const float*)d_in[21];

    char* ws = (char*)d_ws;
    size_t off = 0;
    auto alloc = [&](size_t bytes) -> char* {
        char* p = ws + off;
        off = (off + bytes + 511) & ~(size_t)511;
        return p;
    };
    float* dinvg  = (float*)alloc(NN * 4);
    int*   cntg   = (int*)alloc(NN * 4);
    int*   rstart = (int*)alloc(NN * 4);
    int*   bktcur = (int*)alloc(NB * 4);
    float* accum  = (float*)alloc(1024 * 4);
    float* Wp     = (float*)alloc(1056 * 4);
    float* cp     = Wp + 1024;
    unsigned long long* recs = (unsigned long long*)alloc((size_t)NB * CAPB * 8);
    unsigned long long* csr  = (unsigned long long*)alloc((size_t)NB * CAPB * 8);
    if (off > ws_size) return;  // workspace too small: fail loudly
    // abuf/ybuf alias the bucket-record region (recs dead after k_b2)
    float* abuf = (float*)recs;
    float* ybuf = abuf + (size_t)NN * 32;

    float* st0 = accum;
    float* st1 = accum + 64;
    float* st2 = accum + 128;
    float* st3 = accum + 192;
    float* st4 = accum + 256;
    float* gsum = accum + 320;
    float* gcnt = accum + 576;

    const int GE = (EE + CHUNK - 1) / CHUNK;         // 782
    const int GNODE = (NN * 32 + 255) / 256;         // 12500 half-wave-per-node

    k_init<<<4, 256, 0, stream>>>(bktcur, accum);
    k_bucket<<<GE, 256, 0, stream>>>(ei, ew, bktcur, recs);
    k_b1<<<NB, 256, 0, stream>>>(bktcur, recs, dinvg, cntg, rstart);
    k_b2<<<NB, 256, 0, stream>>>(bktcur, recs, dinvg, rstart, csr);
    k_bn0stats<<<512, 256, 0, stream>>>(x, st0);
    k_fold0<<<1, 512, 0, stream>>>(st0, g0, be0, W1, Wp, cp);
    k_gemm_in<<<GNODE, 256, 0, stream>>>(x, Wp, cp, abuf);
    k_gather<<<2048, 256, 0, stream>>>(abuf, dinvg, rstart, cntg, csr, b1, ybuf, st1);
    k_fold<<<1, 1024, 0, stream>>>(st1, g1, be1, W2, Wp, cp);
    k_gemm<<<GNODE, 256, 0, stream>>>(ybuf, Wp, cp, abuf);
    k_gather<<<2048, 256, 0, stream>>>(abuf, dinvg, rstart, cntg, csr, b2, ybuf, st2);
    k_fold<<<1, 1024, 0, stream>>>(st2, g2, be2, W3, Wp, cp);
    k_gemm<<<GNODE, 256, 0, stream>>>(ybuf, Wp, cp, abuf);
    k_gather<<<2048, 256, 0, stream>>>(abuf, dinvg, rstart, cntg, csr, b3, ybuf, st3);
    k_fold<<<1, 1024, 0, stream>>>(st3, g3, be3, W4, Wp, cp);
    k_gemm<<<GNODE, 256, 0, stream>>>(ybuf, Wp, cp, abuf);
    k_gather<<<2048, 256, 0, stream>>>(abuf, dinvg, rstart, cntg, csr, b4, ybuf, st4);
    k_pool<<<512, 256, 0, stream>>>(ybuf, bat, gsum, gcnt);
    k_final<<<1, 256, 0, stream>>>(st4, gsum, gcnt, g4, be4, (float*)d_out);
}